// Round 1
// baseline (1173.093 us; speedup 1.0000x reference)
//
#include <hip/hip_runtime.h>
#include <hip/hip_bf16.h>

#define N_NODES_DEF 50000
#define HID 128

// ---------------------------------------------------------------------------
// 1) degree init (self-loop counts as 1)
__global__ void init_deg_kernel(int* __restrict__ deg, int n) {
    int i = blockIdx.x * 256 + threadIdx.x;
    if (i < n) deg[i] = 1;
}

// 2) count in-degrees from dst row of edge_index
__global__ void count_kernel(const int* __restrict__ dst, int* __restrict__ deg, int E) {
    int e = blockIdx.x * 256 + threadIdx.x;
    if (e < E) atomicAdd(&deg[dst[e]], 1);
}

// 3) single-block exclusive scan of deg -> row_ptr, cursor; also dinv = rsqrt(deg)
__global__ __launch_bounds__(1024) void scan_kernel(const int* __restrict__ deg,
                                                    int* __restrict__ row_ptr,
                                                    int* __restrict__ cursor,
                                                    float* __restrict__ dinv, int n) {
    __shared__ int part[1024];
    int t = threadIdx.x;
    int chunk = (n + 1023) / 1024;
    int start = t * chunk;
    int end = start + chunk; if (end > n) end = n;
    int s = 0;
    for (int i = start; i < end; ++i) s += deg[i];
    part[t] = s;
    __syncthreads();
    // Hillis-Steele inclusive scan
    for (int off = 1; off < 1024; off <<= 1) {
        int v = part[t];
        int add = (t >= off) ? part[t - off] : 0;
        __syncthreads();
        part[t] = v + add;
        __syncthreads();
    }
    int run = (t == 0) ? 0 : part[t - 1];
    for (int i = start; i < end; ++i) {
        row_ptr[i] = run;
        cursor[i] = run;
        int d = deg[i];
        dinv[i] = rsqrtf((float)d);   // deg >= 1 always
        run += d;
    }
    if (t == 1023) row_ptr[n] = part[1023];
}

// 4) fill CSR columns (edges + implicit self-loops)
__global__ void fill_kernel(const int* __restrict__ src, const int* __restrict__ dst,
                            int* __restrict__ cursor, int* __restrict__ col,
                            int E, int EN) {
    int e = blockIdx.x * 256 + threadIdx.x;
    if (e >= EN) return;
    int s, d;
    if (e < E) { s = src[e]; d = dst[e]; }
    else       { s = e - E; d = s; }
    int pos = atomicAdd(&cursor[d], 1);
    col[pos] = s;
}

// 5) GEMM: out[r][:] = dinv[r] * (A[r][:] @ W)    (M x 128) @ (128 x 128)
//    BM=64, full K=128, full N=128. 256 threads: (tid&31)*4 -> col, (tid>>5)*8 -> rows
__global__ __launch_bounds__(256) void gemm_scale_kernel(const float* __restrict__ A,
                                                         const float* __restrict__ W,
                                                         const float* __restrict__ dinv,
                                                         float* __restrict__ out, int M) {
    __shared__ float sW[128][128];     // 64 KB
    __shared__ float sA[64][132];      // 33.8 KB (pad 132 keeps 16B alignment, breaks bank stride)
    int tid = threadIdx.x;
    int row0 = blockIdx.x * 64;

    for (int i = tid * 4; i < 128 * 128; i += 1024)
        *(float4*)(&sW[0][0] + i) = *(const float4*)(W + i);

    for (int i = tid * 4; i < 64 * 128; i += 1024) {
        int r = i >> 7, c = i & 127;
        float4 v = make_float4(0.f, 0.f, 0.f, 0.f);
        if (row0 + r < M) v = *(const float4*)(A + (size_t)(row0 + r) * 128 + c);
        *(float4*)&sA[r][c] = v;
    }
    __syncthreads();

    int j0 = (tid & 31) * 4;
    int i0 = (tid >> 5) * 8;
    float acc[8][4];
#pragma unroll
    for (int ii = 0; ii < 8; ++ii)
#pragma unroll
        for (int jj = 0; jj < 4; ++jj) acc[ii][jj] = 0.f;

    for (int k = 0; k < 128; k += 4) {
        float4 w0 = *(float4*)&sW[k + 0][j0];
        float4 w1 = *(float4*)&sW[k + 1][j0];
        float4 w2 = *(float4*)&sW[k + 2][j0];
        float4 w3 = *(float4*)&sW[k + 3][j0];
#pragma unroll
        for (int ii = 0; ii < 8; ++ii) {
            float4 a = *(float4*)&sA[i0 + ii][k];
            acc[ii][0] += a.x * w0.x + a.y * w1.x + a.z * w2.x + a.w * w3.x;
            acc[ii][1] += a.x * w0.y + a.y * w1.y + a.z * w2.y + a.w * w3.y;
            acc[ii][2] += a.x * w0.z + a.y * w1.z + a.z * w2.z + a.w * w3.z;
            acc[ii][3] += a.x * w0.w + a.y * w1.w + a.z * w2.w + a.w * w3.w;
        }
    }

#pragma unroll
    for (int ii = 0; ii < 8; ++ii) {
        int r = row0 + i0 + ii;
        if (r < M) {
            float dv = dinv[r];
            float4 o;
            o.x = acc[ii][0] * dv; o.y = acc[ii][1] * dv;
            o.z = acc[ii][2] * dv; o.w = acc[ii][3] * dv;
            *(float4*)(out + (size_t)r * 128 + j0) = o;
        }
    }
}

// 6) aggregation: out[v][:] = relu(dinv[v] * sum_{s in N(v)} hw[s][:] + b)
//    32 lanes per node (float4 per lane), 8 nodes per 256-thread block
__global__ __launch_bounds__(256) void aggregate_kernel(const float* __restrict__ hw,
                                                        const int* __restrict__ row_ptr,
                                                        const int* __restrict__ col,
                                                        const float* __restrict__ dinv,
                                                        const float* __restrict__ bias,
                                                        float* __restrict__ out, int n) {
    int tid = threadIdx.x;
    int v = blockIdx.x * 8 + (tid >> 5);
    if (v >= n) return;
    int j = (tid & 31) * 4;
    int p0 = row_ptr[v], p1 = row_ptr[v + 1];
    float4 acc = make_float4(0.f, 0.f, 0.f, 0.f);
    int p = p0;
    for (; p + 1 < p1; p += 2) {
        int s0 = col[p], s1 = col[p + 1];
        float4 a = *(const float4*)(hw + (size_t)s0 * 128 + j);
        float4 b = *(const float4*)(hw + (size_t)s1 * 128 + j);
        acc.x += a.x + b.x; acc.y += a.y + b.y;
        acc.z += a.z + b.z; acc.w += a.w + b.w;
    }
    if (p < p1) {
        int s0 = col[p];
        float4 a = *(const float4*)(hw + (size_t)s0 * 128 + j);
        acc.x += a.x; acc.y += a.y; acc.z += a.z; acc.w += a.w;
    }
    float dv = dinv[v];
    float4 bb = *(const float4*)(bias + j);
    float4 o;
    o.x = fmaxf(acc.x * dv + bb.x, 0.f);
    o.y = fmaxf(acc.y * dv + bb.y, 0.f);
    o.z = fmaxf(acc.z * dv + bb.z, 0.f);
    o.w = fmaxf(acc.w * dv + bb.w, 0.f);
    *(float4*)(out + (size_t)v * 128 + j) = o;
}

// 7) zero pool accumulators
__global__ void pool_zero_kernel(float* __restrict__ sums, int* __restrict__ cnt) {
    int i = blockIdx.x * 256 + threadIdx.x;
    if (i < 64 * 128) sums[i] = 0.f;
    if (i < 64) cnt[i] = 0;
}

// 8) pooled sums via atomics (batch-sorted; contention is only ~780 adds/addr)
__global__ __launch_bounds__(256) void pool_kernel(const float* __restrict__ h,
                                                   const int* __restrict__ batch,
                                                   float* __restrict__ sums,
                                                   int* __restrict__ cnt, int n) {
    int tid = threadIdx.x;
    int v = blockIdx.x * 8 + (tid >> 5);
    if (v >= n) return;
    int j = (tid & 31) * 4;
    int g = batch[v];
    float4 a = *(const float4*)(h + (size_t)v * 128 + j);
    float* s = sums + g * 128 + j;
    atomicAdd(s + 0, a.x); atomicAdd(s + 1, a.y);
    atomicAdd(s + 2, a.z); atomicAdd(s + 3, a.w);
    if ((tid & 31) == 0) atomicAdd(&cnt[g], 1);
}

// 9) final MLP: out = relu(pooled @ W1 + b1) @ W2 + b2, single block
__global__ __launch_bounds__(256) void mlp_kernel(const float* __restrict__ sums,
                                                  const int* __restrict__ cnt,
                                                  const float* __restrict__ W1,
                                                  const float* __restrict__ b1,
                                                  const float* __restrict__ W2,
                                                  const float* __restrict__ b2,
                                                  float* __restrict__ out) {
    __shared__ float pooled[64][128];
    __shared__ float h1[64][64];
    int tid = threadIdx.x;
    for (int i = tid; i < 64 * 128; i += 256) {
        int g = i >> 7;
        int c = cnt[g]; if (c < 1) c = 1;
        pooled[g][i & 127] = sums[i] / (float)c;
    }
    __syncthreads();
    for (int i = tid; i < 64 * 64; i += 256) {
        int g = i >> 6, j = i & 63;
        float acc = b1[j];
        for (int k = 0; k < 128; ++k) acc += pooled[g][k] * W1[k * 64 + j];
        h1[g][j] = fmaxf(acc, 0.f);
    }
    __syncthreads();
    if (tid < 128) {
        int g = tid >> 1, c = tid & 1;
        float acc = b2[c];
        for (int jj = 0; jj < 64; ++jj) acc += h1[g][jj] * W2[jj * 2 + c];
        out[tid] = acc;
    }
}

// ---------------------------------------------------------------------------
extern "C" void kernel_launch(void* const* d_in, const int* in_sizes, int n_in,
                              void* d_out, int out_size, void* d_ws, size_t ws_size,
                              hipStream_t stream) {
    const float* x    = (const float*)d_in[0];
    const int*   ei   = (const int*)d_in[1];
    const int*   batch= (const int*)d_in[2];
    const float* W0   = (const float*)d_in[3];
    const float* b0   = (const float*)d_in[4];
    const float* Ws   = (const float*)d_in[5];
    const float* bs   = (const float*)d_in[6];
    const float* W1   = (const float*)d_in[7];
    const float* b1   = (const float*)d_in[8];
    const float* W2   = (const float*)d_in[9];
    const float* b2   = (const float*)d_in[10];
    float* out = (float*)d_out;

    const int n  = in_sizes[0] / HID;      // 50000
    const int E  = in_sizes[1] / 2;        // 800000
    const int EN = E + n;                  // 850000
    const int* src = ei;
    const int* dst = ei + E;

    // workspace layout (16B aligned chunks)
    char* ws = (char*)d_ws;
    size_t off = 0;
    auto alloc = [&](size_t bytes) { void* p = ws + off; off = (off + bytes + 255) & ~(size_t)255; return p; };
    float* bufA   = (float*)alloc((size_t)n * HID * 4);
    float* bufB   = (float*)alloc((size_t)n * HID * 4);
    float* dinv   = (float*)alloc((size_t)n * 4);
    int*   row_ptr= (int*)  alloc((size_t)(n + 1) * 4);
    int*   cursor = (int*)  alloc((size_t)n * 4);
    int*   deg    = (int*)  alloc((size_t)n * 4);
    int*   col    = (int*)  alloc((size_t)EN * 4);
    float* sums   = (float*)alloc(64 * 128 * 4);
    int*   cnt    = (int*)  alloc(64 * 4);
    (void)ws_size; (void)n_in; (void)out_size;

    // --- build normalized CSR ---
    init_deg_kernel<<<(n + 255) / 256, 256, 0, stream>>>(deg, n);
    count_kernel<<<(E + 255) / 256, 256, 0, stream>>>(dst, deg, E);
    scan_kernel<<<1, 1024, 0, stream>>>(deg, row_ptr, cursor, dinv, n);
    fill_kernel<<<(EN + 255) / 256, 256, 0, stream>>>(src, dst, cursor, col, E, EN);

    const int gemm_grid = (n + 63) / 64;
    const int node_grid = (n + 7) / 8;

    // --- layer 0 ---
    gemm_scale_kernel<<<gemm_grid, 256, 0, stream>>>(x, W0, dinv, bufB, n);
    aggregate_kernel<<<node_grid, 256, 0, stream>>>(bufB, row_ptr, col, dinv, b0, bufA, n);
    // --- layers 1..3 ---
    for (int l = 0; l < 3; ++l) {
        gemm_scale_kernel<<<gemm_grid, 256, 0, stream>>>(bufA, Ws + (size_t)l * HID * HID, dinv, bufB, n);
        aggregate_kernel<<<node_grid, 256, 0, stream>>>(bufB, row_ptr, col, dinv, bs + (size_t)l * HID, bufA, n);
    }

    // --- pooling + MLP ---
    pool_zero_kernel<<<33, 256, 0, stream>>>(sums, cnt);
    pool_kernel<<<node_grid, 256, 0, stream>>>(bufA, batch, sums, cnt, n);
    mlp_kernel<<<1, 256, 0, stream>>>(sums, cnt, W1, b1, W2, b2, out);
}

// Round 2
// 838.006 us; speedup vs baseline: 1.3999x; 1.3999x over previous
//
#include <hip/hip_runtime.h>
#include <hip/hip_bf16.h>

#define HID 128
#define N_GRAPHS 64

// ---------------------------------------------------------------------------
// 1) degree init (self-loop counts as 1)
__global__ void init_deg_kernel(int* __restrict__ deg, int n) {
    int i = blockIdx.x * 256 + threadIdx.x;
    if (i < n) deg[i] = 1;
}

// 2) count in-degrees from dst row of edge_index
__global__ void count_kernel(const int* __restrict__ dst, int* __restrict__ deg, int E) {
    int e = blockIdx.x * 256 + threadIdx.x;
    if (e < E) atomicAdd(&deg[dst[e]], 1);
}

// 3) single-block exclusive scan of deg -> row_ptr, cursor; also dinv = rsqrt(deg)
__global__ __launch_bounds__(1024) void scan_kernel(const int* __restrict__ deg,
                                                    int* __restrict__ row_ptr,
                                                    int* __restrict__ cursor,
                                                    float* __restrict__ dinv, int n) {
    __shared__ int part[1024];
    int t = threadIdx.x;
    int chunk = (n + 1023) / 1024;
    int start = t * chunk;
    int end = start + chunk; if (end > n) end = n;
    int s = 0;
    for (int i = start; i < end; ++i) s += deg[i];
    part[t] = s;
    __syncthreads();
    for (int off = 1; off < 1024; off <<= 1) {
        int v = part[t];
        int add = (t >= off) ? part[t - off] : 0;
        __syncthreads();
        part[t] = v + add;
        __syncthreads();
    }
    int run = (t == 0) ? 0 : part[t - 1];
    for (int i = start; i < end; ++i) {
        row_ptr[i] = run;
        cursor[i] = run;
        int d = deg[i];
        dinv[i] = rsqrtf((float)d);
        run += d;
    }
    if (t == 1023) row_ptr[n] = part[1023];
}

// 4) fill CSR columns (edges + implicit self-loops)
__global__ void fill_kernel(const int* __restrict__ src, const int* __restrict__ dst,
                            int* __restrict__ cursor, int* __restrict__ col,
                            int E, int EN) {
    int e = blockIdx.x * 256 + threadIdx.x;
    if (e >= EN) return;
    int s, d;
    if (e < E) { s = src[e]; d = dst[e]; }
    else       { s = e - E; d = s; }
    int pos = atomicAdd(&cursor[d], 1);
    col[pos] = s;
}

// 5) GEMM: out[r][:] = dinv[r] * (A[r][:] @ W)    (M x 128) @ (128 x 128)
__global__ __launch_bounds__(256) void gemm_scale_kernel(const float* __restrict__ A,
                                                         const float* __restrict__ W,
                                                         const float* __restrict__ dinv,
                                                         float* __restrict__ out, int M) {
    __shared__ float sW[128][128];
    __shared__ float sA[64][132];
    int tid = threadIdx.x;
    int row0 = blockIdx.x * 64;

    for (int i = tid * 4; i < 128 * 128; i += 1024)
        *(float4*)(&sW[0][0] + i) = *(const float4*)(W + i);

    for (int i = tid * 4; i < 64 * 128; i += 1024) {
        int r = i >> 7, c = i & 127;
        float4 v = make_float4(0.f, 0.f, 0.f, 0.f);
        if (row0 + r < M) v = *(const float4*)(A + (size_t)(row0 + r) * 128 + c);
        *(float4*)&sA[r][c] = v;
    }
    __syncthreads();

    int j0 = (tid & 31) * 4;
    int i0 = (tid >> 5) * 8;
    float acc[8][4];
#pragma unroll
    for (int ii = 0; ii < 8; ++ii)
#pragma unroll
        for (int jj = 0; jj < 4; ++jj) acc[ii][jj] = 0.f;

    for (int k = 0; k < 128; k += 4) {
        float4 w0 = *(float4*)&sW[k + 0][j0];
        float4 w1 = *(float4*)&sW[k + 1][j0];
        float4 w2 = *(float4*)&sW[k + 2][j0];
        float4 w3 = *(float4*)&sW[k + 3][j0];
#pragma unroll
        for (int ii = 0; ii < 8; ++ii) {
            float4 a = *(float4*)&sA[i0 + ii][k];
            acc[ii][0] += a.x * w0.x + a.y * w1.x + a.z * w2.x + a.w * w3.x;
            acc[ii][1] += a.x * w0.y + a.y * w1.y + a.z * w2.y + a.w * w3.y;
            acc[ii][2] += a.x * w0.z + a.y * w1.z + a.z * w2.z + a.w * w3.z;
            acc[ii][3] += a.x * w0.w + a.y * w1.w + a.z * w2.w + a.w * w3.w;
        }
    }

#pragma unroll
    for (int ii = 0; ii < 8; ++ii) {
        int r = row0 + i0 + ii;
        if (r < M) {
            float dv = dinv[r];
            float4 o;
            o.x = acc[ii][0] * dv; o.y = acc[ii][1] * dv;
            o.z = acc[ii][2] * dv; o.w = acc[ii][3] * dv;
            *(float4*)(out + (size_t)r * 128 + j0) = o;
        }
    }
}

// 6) aggregation: out[v][:] = relu(dinv[v] * sum_{s in N(v)} hw[s][:] + b)
__global__ __launch_bounds__(256) void aggregate_kernel(const float* __restrict__ hw,
                                                        const int* __restrict__ row_ptr,
                                                        const int* __restrict__ col,
                                                        const float* __restrict__ dinv,
                                                        const float* __restrict__ bias,
                                                        float* __restrict__ out, int n) {
    int tid = threadIdx.x;
    int v = blockIdx.x * 8 + (tid >> 5);
    if (v >= n) return;
    int j = (tid & 31) * 4;
    int p0 = row_ptr[v], p1 = row_ptr[v + 1];
    float4 acc = make_float4(0.f, 0.f, 0.f, 0.f);
    int p = p0;
    for (; p + 1 < p1; p += 2) {
        int s0 = col[p], s1 = col[p + 1];
        float4 a = *(const float4*)(hw + (size_t)s0 * 128 + j);
        float4 b = *(const float4*)(hw + (size_t)s1 * 128 + j);
        acc.x += a.x + b.x; acc.y += a.y + b.y;
        acc.z += a.z + b.z; acc.w += a.w + b.w;
    }
    if (p < p1) {
        int s0 = col[p];
        float4 a = *(const float4*)(hw + (size_t)s0 * 128 + j);
        acc.x += a.x; acc.y += a.y; acc.z += a.z; acc.w += a.w;
    }
    float dv = dinv[v];
    float4 bb = *(const float4*)(bias + j);
    float4 o;
    o.x = fmaxf(acc.x * dv + bb.x, 0.f);
    o.y = fmaxf(acc.y * dv + bb.y, 0.f);
    o.z = fmaxf(acc.z * dv + bb.z, 0.f);
    o.w = fmaxf(acc.w * dv + bb.w, 0.f);
    *(float4*)(out + (size_t)v * 128 + j) = o;
}

// 7) graph boundary detection (batch is sorted): start[g] = first node of graph g,
//    start[N_GRAPHS] = n. Handles empty graphs.
__global__ void boundary_kernel(const int* __restrict__ batch, int* __restrict__ start, int n) {
    int i = blockIdx.x * 256 + threadIdx.x;
    if (i >= n) return;
    int b = batch[i];
    int pb = (i > 0) ? batch[i - 1] : -1;
    if (b != pb) {
        for (int g = pb + 1; g <= b; ++g) start[g] = i;
    }
    if (i == n - 1) {
        for (int g = b + 1; g <= N_GRAPHS; ++g) start[g] = n;
    }
}

// 8) pooled mean per graph: one block per graph, no atomics.
//    8 row-groups x 32 lanes x float4; LDS tree reduce across groups.
__global__ __launch_bounds__(256) void pool_reduce_kernel(const float* __restrict__ h,
                                                          const int* __restrict__ start,
                                                          float* __restrict__ pooled) {
    __shared__ float part[8][128];
    int g = blockIdx.x;
    int s = start[g], e = start[g + 1];
    int tid = threadIdx.x;
    int grp = tid >> 5;
    int j = (tid & 31) * 4;
    float4 acc = make_float4(0.f, 0.f, 0.f, 0.f);
    for (int v = s + grp; v < e; v += 8) {
        float4 a = *(const float4*)(h + (size_t)v * 128 + j);
        acc.x += a.x; acc.y += a.y; acc.z += a.z; acc.w += a.w;
    }
    *(float4*)&part[grp][j] = acc;
    __syncthreads();
    if (tid < 128) {
        float sum = 0.f;
#pragma unroll
        for (int k = 0; k < 8; ++k) sum += part[k][tid];
        int cntv = e - s; if (cntv < 1) cntv = 1;
        pooled[g * 128 + tid] = sum / (float)cntv;
    }
}

// 9) final MLP: out = relu(pooled @ W1 + b1) @ W2 + b2, single block
__global__ __launch_bounds__(256) void mlp_kernel(const float* __restrict__ pooled_g,
                                                  const float* __restrict__ W1,
                                                  const float* __restrict__ b1,
                                                  const float* __restrict__ W2,
                                                  const float* __restrict__ b2,
                                                  float* __restrict__ out) {
    __shared__ float pooled[64][128];
    __shared__ float h1[64][64];
    int tid = threadIdx.x;
    for (int i = tid; i < 64 * 128; i += 256) pooled[i >> 7][i & 127] = pooled_g[i];
    __syncthreads();
    for (int i = tid; i < 64 * 64; i += 256) {
        int g = i >> 6, j = i & 63;
        float acc = b1[j];
        for (int k = 0; k < 128; ++k) acc += pooled[g][k] * W1[k * 64 + j];
        h1[g][j] = fmaxf(acc, 0.f);
    }
    __syncthreads();
    if (tid < 128) {
        int g = tid >> 1, c = tid & 1;
        float acc = b2[c];
        for (int jj = 0; jj < 64; ++jj) acc += h1[g][jj] * W2[jj * 2 + c];
        out[tid] = acc;
    }
}

// ---------------------------------------------------------------------------
extern "C" void kernel_launch(void* const* d_in, const int* in_sizes, int n_in,
                              void* d_out, int out_size, void* d_ws, size_t ws_size,
                              hipStream_t stream) {
    const float* x    = (const float*)d_in[0];
    const int*   ei   = (const int*)d_in[1];
    const int*   batch= (const int*)d_in[2];
    const float* W0   = (const float*)d_in[3];
    const float* b0   = (const float*)d_in[4];
    const float* Ws   = (const float*)d_in[5];
    const float* bs   = (const float*)d_in[6];
    const float* W1   = (const float*)d_in[7];
    const float* b1   = (const float*)d_in[8];
    const float* W2   = (const float*)d_in[9];
    const float* b2   = (const float*)d_in[10];
    float* out = (float*)d_out;

    const int n  = in_sizes[0] / HID;      // 50000
    const int E  = in_sizes[1] / 2;        // 800000
    const int EN = E + n;                  // 850000
    const int* src = ei;
    const int* dst = ei + E;

    char* ws = (char*)d_ws;
    size_t off = 0;
    auto alloc = [&](size_t bytes) { void* p = ws + off; off = (off + bytes + 255) & ~(size_t)255; return p; };
    float* bufA   = (float*)alloc((size_t)n * HID * 4);
    float* bufB   = (float*)alloc((size_t)n * HID * 4);
    float* dinv   = (float*)alloc((size_t)n * 4);
    int*   row_ptr= (int*)  alloc((size_t)(n + 1) * 4);
    int*   cursor = (int*)  alloc((size_t)n * 4);
    int*   deg    = (int*)  alloc((size_t)n * 4);
    int*   col    = (int*)  alloc((size_t)EN * 4);
    int*   gstart = (int*)  alloc((N_GRAPHS + 1) * 4);
    float* pooled = (float*)alloc(N_GRAPHS * 128 * 4);
    (void)ws_size; (void)n_in; (void)out_size;

    // --- build normalized CSR ---
    init_deg_kernel<<<(n + 255) / 256, 256, 0, stream>>>(deg, n);
    count_kernel<<<(E + 255) / 256, 256, 0, stream>>>(dst, deg, E);
    scan_kernel<<<1, 1024, 0, stream>>>(deg, row_ptr, cursor, dinv, n);
    fill_kernel<<<(EN + 255) / 256, 256, 0, stream>>>(src, dst, cursor, col, E, EN);
    boundary_kernel<<<(n + 255) / 256, 256, 0, stream>>>(batch, gstart, n);

    const int gemm_grid = (n + 63) / 64;
    const int node_grid = (n + 7) / 8;

    // --- layer 0 ---
    gemm_scale_kernel<<<gemm_grid, 256, 0, stream>>>(x, W0, dinv, bufB, n);
    aggregate_kernel<<<node_grid, 256, 0, stream>>>(bufB, row_ptr, col, dinv, b0, bufA, n);
    // --- layers 1..3 ---
    for (int l = 0; l < 3; ++l) {
        gemm_scale_kernel<<<gemm_grid, 256, 0, stream>>>(bufA, Ws + (size_t)l * HID * HID, dinv, bufB, n);
        aggregate_kernel<<<node_grid, 256, 0, stream>>>(bufB, row_ptr, col, dinv, bs + (size_t)l * HID, bufA, n);
    }

    // --- pooling + MLP ---
    pool_reduce_kernel<<<N_GRAPHS, 256, 0, stream>>>(bufA, gstart, pooled);
    mlp_kernel<<<1, 256, 0, stream>>>(pooled, W1, b1, W2, b2, out);
}

// Round 3
// 620.636 us; speedup vs baseline: 1.8901x; 1.3502x over previous
//
#include <hip/hip_runtime.h>
#include <hip/hip_bf16.h>

#define HID 128
#define N_GRAPHS 64

// ---------------------------------------------------------------------------
// 1) degree init (self-loop counts as 1)
__global__ void init_deg_kernel(int* __restrict__ deg, int n) {
    int i = blockIdx.x * 256 + threadIdx.x;
    if (i < n) deg[i] = 1;
}

// 2) count in-degrees from dst row of edge_index
__global__ void count_kernel(const int* __restrict__ dst, int* __restrict__ deg, int E) {
    int e = blockIdx.x * 256 + threadIdx.x;
    if (e < E) atomicAdd(&deg[dst[e]], 1);
}

// 3a) per-block partial sums of deg
__global__ __launch_bounds__(256) void scan_partial_kernel(const int* __restrict__ deg,
                                                           int* __restrict__ bsum, int n) {
    __shared__ int red[256];
    int t = threadIdx.x;
    int i = blockIdx.x * 256 + t;
    red[t] = (i < n) ? deg[i] : 0;
    __syncthreads();
#pragma unroll
    for (int s = 128; s > 0; s >>= 1) {
        if (t < s) red[t] += red[t + s];
        __syncthreads();
    }
    if (t == 0) bsum[blockIdx.x] = red[0];
}

// 3b) single-block exclusive scan of block sums (nb <= 256); also writes row_ptr[n]
__global__ __launch_bounds__(256) void scan_bsum_kernel(const int* __restrict__ bsum,
                                                        int* __restrict__ boff,
                                                        int* __restrict__ row_ptr,
                                                        int nb, int n) {
    __shared__ int arr[256];
    int t = threadIdx.x;
    int own = (t < nb) ? bsum[t] : 0;
    arr[t] = own;
    __syncthreads();
#pragma unroll
    for (int off = 1; off < 256; off <<= 1) {
        int v = arr[t];
        int add = (t >= off) ? arr[t - off] : 0;
        __syncthreads();
        arr[t] = v + add;
        __syncthreads();
    }
    if (t < nb) boff[t] = arr[t] - own;        // exclusive
    if (t == 255) row_ptr[n] = arr[255];       // total
}

// 3c) emit row_ptr/cursor/dinv via in-block exclusive scan + block offset
__global__ __launch_bounds__(256) void scan_emit_kernel(const int* __restrict__ deg,
                                                        const int* __restrict__ boff,
                                                        int* __restrict__ row_ptr,
                                                        int* __restrict__ cursor,
                                                        float* __restrict__ dinv, int n) {
    __shared__ int arr[256];
    int t = threadIdx.x;
    int i = blockIdx.x * 256 + t;
    int d = (i < n) ? deg[i] : 0;
    arr[t] = d;
    __syncthreads();
#pragma unroll
    for (int off = 1; off < 256; off <<= 1) {
        int v = arr[t];
        int add = (t >= off) ? arr[t - off] : 0;
        __syncthreads();
        arr[t] = v + add;
        __syncthreads();
    }
    if (i < n) {
        int pos = boff[blockIdx.x] + arr[t] - d;   // exclusive prefix
        row_ptr[i] = pos;
        cursor[i] = pos;
        dinv[i] = rsqrtf((float)d);
    }
}

// 4) fill CSR columns (edges + implicit self-loops)
__global__ void fill_kernel(const int* __restrict__ src, const int* __restrict__ dst,
                            int* __restrict__ cursor, int* __restrict__ col,
                            int E, int EN) {
    int e = blockIdx.x * 256 + threadIdx.x;
    if (e >= EN) return;
    int s, d;
    if (e < E) { s = src[e]; d = dst[e]; }
    else       { s = e - E; d = s; }
    int pos = atomicAdd(&cursor[d], 1);
    col[pos] = s;
}

// 5) GEMM: out[r][:] = dinv[r] * (A[r][:] @ W), K chunked in halves of 64.
//    LDS: sW 32KB + sA 17KB = 49.4KB -> 3 blocks/CU (12 waves/CU).
__global__ __launch_bounds__(256) void gemm_scale_kernel(const float* __restrict__ A,
                                                         const float* __restrict__ W,
                                                         const float* __restrict__ dinv,
                                                         float* __restrict__ out, int M) {
    __shared__ float sW[64][128];
    __shared__ float sA[64][68];
    int tid = threadIdx.x;
    int row0 = blockIdx.x * 64;
    int j0 = (tid & 31) * 4;
    int i0 = (tid >> 5) * 8;

    float acc[8][4];
#pragma unroll
    for (int ii = 0; ii < 8; ++ii)
#pragma unroll
        for (int jj = 0; jj < 4; ++jj) acc[ii][jj] = 0.f;

    for (int kc = 0; kc < 2; ++kc) {
        // W chunk: rows kc*64 .. kc*64+63 (contiguous 8192 floats)
        for (int idx = tid * 4; idx < 64 * 128; idx += 1024)
            *(float4*)(&sW[0][0] + idx) = *(const float4*)(W + (size_t)kc * 64 * 128 + idx);
        // A chunk: 64 rows x 64 cols
        for (int idx = tid * 4; idx < 64 * 64; idx += 1024) {
            int r = idx >> 6, c = idx & 63;
            float4 v = make_float4(0.f, 0.f, 0.f, 0.f);
            if (row0 + r < M) v = *(const float4*)(A + (size_t)(row0 + r) * 128 + kc * 64 + c);
            *(float4*)&sA[r][c] = v;
        }
        __syncthreads();

        for (int k = 0; k < 64; k += 4) {
            float4 w0 = *(float4*)&sW[k + 0][j0];
            float4 w1 = *(float4*)&sW[k + 1][j0];
            float4 w2 = *(float4*)&sW[k + 2][j0];
            float4 w3 = *(float4*)&sW[k + 3][j0];
#pragma unroll
            for (int ii = 0; ii < 8; ++ii) {
                float4 a = *(float4*)&sA[i0 + ii][k];
                acc[ii][0] += a.x * w0.x + a.y * w1.x + a.z * w2.x + a.w * w3.x;
                acc[ii][1] += a.x * w0.y + a.y * w1.y + a.z * w2.y + a.w * w3.y;
                acc[ii][2] += a.x * w0.z + a.y * w1.z + a.z * w2.z + a.w * w3.z;
                acc[ii][3] += a.x * w0.w + a.y * w1.w + a.z * w2.w + a.w * w3.w;
            }
        }
        __syncthreads();
    }

#pragma unroll
    for (int ii = 0; ii < 8; ++ii) {
        int r = row0 + i0 + ii;
        if (r < M) {
            float dv = dinv[r];
            float4 o;
            o.x = acc[ii][0] * dv; o.y = acc[ii][1] * dv;
            o.z = acc[ii][2] * dv; o.w = acc[ii][3] * dv;
            *(float4*)(out + (size_t)r * 128 + j0) = o;
        }
    }
}

// 6) aggregation: out[v][:] = relu(dinv[v] * sum_{s in N(v)} hw[s][:] + b)
__global__ __launch_bounds__(256) void aggregate_kernel(const float* __restrict__ hw,
                                                        const int* __restrict__ row_ptr,
                                                        const int* __restrict__ col,
                                                        const float* __restrict__ dinv,
                                                        const float* __restrict__ bias,
                                                        float* __restrict__ out, int n) {
    int tid = threadIdx.x;
    int v = blockIdx.x * 8 + (tid >> 5);
    if (v >= n) return;
    int j = (tid & 31) * 4;
    int p0 = row_ptr[v], p1 = row_ptr[v + 1];
    float4 acc = make_float4(0.f, 0.f, 0.f, 0.f);
    int p = p0;
    for (; p + 1 < p1; p += 2) {
        int s0 = col[p], s1 = col[p + 1];
        float4 a = *(const float4*)(hw + (size_t)s0 * 128 + j);
        float4 b = *(const float4*)(hw + (size_t)s1 * 128 + j);
        acc.x += a.x + b.x; acc.y += a.y + b.y;
        acc.z += a.z + b.z; acc.w += a.w + b.w;
    }
    if (p < p1) {
        int s0 = col[p];
        float4 a = *(const float4*)(hw + (size_t)s0 * 128 + j);
        acc.x += a.x; acc.y += a.y; acc.z += a.z; acc.w += a.w;
    }
    float dv = dinv[v];
    float4 bb = *(const float4*)(bias + j);
    float4 o;
    o.x = fmaxf(acc.x * dv + bb.x, 0.f);
    o.y = fmaxf(acc.y * dv + bb.y, 0.f);
    o.z = fmaxf(acc.z * dv + bb.z, 0.f);
    o.w = fmaxf(acc.w * dv + bb.w, 0.f);
    *(float4*)(out + (size_t)v * 128 + j) = o;
}

// 7) graph boundary detection (batch sorted)
__global__ void boundary_kernel(const int* __restrict__ batch, int* __restrict__ start, int n) {
    int i = blockIdx.x * 256 + threadIdx.x;
    if (i >= n) return;
    int b = batch[i];
    int pb = (i > 0) ? batch[i - 1] : -1;
    if (b != pb) {
        for (int g = pb + 1; g <= b; ++g) start[g] = i;
    }
    if (i == n - 1) {
        for (int g = b + 1; g <= N_GRAPHS; ++g) start[g] = n;
    }
}

// 8) pooled mean per graph: one block per graph, no atomics
__global__ __launch_bounds__(256) void pool_reduce_kernel(const float* __restrict__ h,
                                                          const int* __restrict__ start,
                                                          float* __restrict__ pooled) {
    __shared__ float part[8][128];
    int g = blockIdx.x;
    int s = start[g], e = start[g + 1];
    int tid = threadIdx.x;
    int grp = tid >> 5;
    int j = (tid & 31) * 4;
    float4 acc = make_float4(0.f, 0.f, 0.f, 0.f);
    for (int v = s + grp; v < e; v += 8) {
        float4 a = *(const float4*)(h + (size_t)v * 128 + j);
        acc.x += a.x; acc.y += a.y; acc.z += a.z; acc.w += a.w;
    }
    *(float4*)&part[grp][j] = acc;
    __syncthreads();
    if (tid < 128) {
        float sum = 0.f;
#pragma unroll
        for (int k = 0; k < 8; ++k) sum += part[k][tid];
        int cntv = e - s; if (cntv < 1) cntv = 1;
        pooled[g * 128 + tid] = sum / (float)cntv;
    }
}

// 9) final MLP
__global__ __launch_bounds__(256) void mlp_kernel(const float* __restrict__ pooled_g,
                                                  const float* __restrict__ W1,
                                                  const float* __restrict__ b1,
                                                  const float* __restrict__ W2,
                                                  const float* __restrict__ b2,
                                                  float* __restrict__ out) {
    __shared__ float pooled[64][128];
    __shared__ float h1[64][64];
    int tid = threadIdx.x;
    for (int i = tid; i < 64 * 128; i += 256) pooled[i >> 7][i & 127] = pooled_g[i];
    __syncthreads();
    for (int i = tid; i < 64 * 64; i += 256) {
        int g = i >> 6, j = i & 63;
        float acc = b1[j];
        for (int k = 0; k < 128; ++k) acc += pooled[g][k] * W1[k * 64 + j];
        h1[g][j] = fmaxf(acc, 0.f);
    }
    __syncthreads();
    if (tid < 128) {
        int g = tid >> 1, c = tid & 1;
        float acc = b2[c];
        for (int jj = 0; jj < 64; ++jj) acc += h1[g][jj] * W2[jj * 2 + c];
        out[tid] = acc;
    }
}

// ---------------------------------------------------------------------------
extern "C" void kernel_launch(void* const* d_in, const int* in_sizes, int n_in,
                              void* d_out, int out_size, void* d_ws, size_t ws_size,
                              hipStream_t stream) {
    const float* x    = (const float*)d_in[0];
    const int*   ei   = (const int*)d_in[1];
    const int*   batch= (const int*)d_in[2];
    const float* W0   = (const float*)d_in[3];
    const float* b0   = (const float*)d_in[4];
    const float* Ws   = (const float*)d_in[5];
    const float* bs   = (const float*)d_in[6];
    const float* W1   = (const float*)d_in[7];
    const float* b1   = (const float*)d_in[8];
    const float* W2   = (const float*)d_in[9];
    const float* b2   = (const float*)d_in[10];
    float* out = (float*)d_out;

    const int n  = in_sizes[0] / HID;      // 50000
    const int E  = in_sizes[1] / 2;        // 800000
    const int EN = E + n;                  // 850000
    const int* src = ei;
    const int* dst = ei + E;
    const int nb = (n + 255) / 256;        // 196 blocks (<=256 for 1-block bsum scan)

    char* ws = (char*)d_ws;
    size_t off = 0;
    auto alloc = [&](size_t bytes) { void* p = ws + off; off = (off + bytes + 255) & ~(size_t)255; return p; };
    float* bufA   = (float*)alloc((size_t)n * HID * 4);
    float* bufB   = (float*)alloc((size_t)n * HID * 4);
    float* dinv   = (float*)alloc((size_t)n * 4);
    int*   row_ptr= (int*)  alloc((size_t)(n + 1) * 4);
    int*   cursor = (int*)  alloc((size_t)n * 4);
    int*   deg    = (int*)  alloc((size_t)n * 4);
    int*   col    = (int*)  alloc((size_t)EN * 4);
    int*   bsum   = (int*)  alloc((size_t)nb * 4);
    int*   boff   = (int*)  alloc((size_t)nb * 4);
    int*   gstart = (int*)  alloc((N_GRAPHS + 1) * 4);
    float* pooled = (float*)alloc(N_GRAPHS * 128 * 4);
    (void)ws_size; (void)n_in; (void)out_size;

    // --- build normalized CSR ---
    init_deg_kernel<<<nb, 256, 0, stream>>>(deg, n);
    count_kernel<<<(E + 255) / 256, 256, 0, stream>>>(dst, deg, E);
    scan_partial_kernel<<<nb, 256, 0, stream>>>(deg, bsum, n);
    scan_bsum_kernel<<<1, 256, 0, stream>>>(bsum, boff, row_ptr, nb, n);
    scan_emit_kernel<<<nb, 256, 0, stream>>>(deg, boff, row_ptr, cursor, dinv, n);
    fill_kernel<<<(EN + 255) / 256, 256, 0, stream>>>(src, dst, cursor, col, E, EN);
    boundary_kernel<<<nb, 256, 0, stream>>>(batch, gstart, n);

    const int gemm_grid = (n + 63) / 64;
    const int node_grid = (n + 7) / 8;

    // --- layer 0 ---
    gemm_scale_kernel<<<gemm_grid, 256, 0, stream>>>(x, W0, dinv, bufB, n);
    aggregate_kernel<<<node_grid, 256, 0, stream>>>(bufB, row_ptr, col, dinv, b0, bufA, n);
    // --- layers 1..3 ---
    for (int l = 0; l < 3; ++l) {
        gemm_scale_kernel<<<gemm_grid, 256, 0, stream>>>(bufA, Ws + (size_t)l * HID * HID, dinv, bufB, n);
        aggregate_kernel<<<node_grid, 256, 0, stream>>>(bufB, row_ptr, col, dinv, bs + (size_t)l * HID, bufA, n);
    }

    // --- pooling + MLP ---
    pool_reduce_kernel<<<N_GRAPHS, 256, 0, stream>>>(bufA, gstart, pooled);
    mlp_kernel<<<1, 256, 0, stream>>>(pooled, W1, b1, W2, b2, out);
}

// Round 5
// 611.443 us; speedup vs baseline: 1.9186x; 1.0150x over previous
//
#include <hip/hip_runtime.h>
#include <hip/hip_bf16.h>

#define HID 128
#define N_GRAPHS 64

// ---------------------------------------------------------------------------
// 1) degree init (self-loop counts as 1)
__global__ void init_deg_kernel(int* __restrict__ deg, int n) {
    int i = blockIdx.x * 256 + threadIdx.x;
    if (i < n) deg[i] = 1;
}

// 2) count in-degrees from dst row of edge_index
__global__ void count_kernel(const int* __restrict__ dst, int* __restrict__ deg, int E) {
    int e = blockIdx.x * 256 + threadIdx.x;
    if (e < E) atomicAdd(&deg[dst[e]], 1);
}

// 3a) per-block partial sums of deg
__global__ __launch_bounds__(256) void scan_partial_kernel(const int* __restrict__ deg,
                                                           int* __restrict__ bsum, int n) {
    __shared__ int red[256];
    int t = threadIdx.x;
    int i = blockIdx.x * 256 + t;
    red[t] = (i < n) ? deg[i] : 0;
    __syncthreads();
#pragma unroll
    for (int s = 128; s > 0; s >>= 1) {
        if (t < s) red[t] += red[t + s];
        __syncthreads();
    }
    if (t == 0) bsum[blockIdx.x] = red[0];
}

// 3b) single-block exclusive scan of block sums (nb <= 256); also writes row_ptr[n]
__global__ __launch_bounds__(256) void scan_bsum_kernel(const int* __restrict__ bsum,
                                                        int* __restrict__ boff,
                                                        int* __restrict__ row_ptr,
                                                        int nb, int n) {
    __shared__ int arr[256];
    int t = threadIdx.x;
    int own = (t < nb) ? bsum[t] : 0;
    arr[t] = own;
    __syncthreads();
#pragma unroll
    for (int off = 1; off < 256; off <<= 1) {
        int v = arr[t];
        int add = (t >= off) ? arr[t - off] : 0;
        __syncthreads();
        arr[t] = v + add;
        __syncthreads();
    }
    if (t < nb) boff[t] = arr[t] - own;        // exclusive
    if (t == 255) row_ptr[n] = arr[255];       // total
}

// 3c) emit row_ptr/cursor/dinv via in-block exclusive scan + block offset
__global__ __launch_bounds__(256) void scan_emit_kernel(const int* __restrict__ deg,
                                                        const int* __restrict__ boff,
                                                        int* __restrict__ row_ptr,
                                                        int* __restrict__ cursor,
                                                        float* __restrict__ dinv, int n) {
    __shared__ int arr[256];
    int t = threadIdx.x;
    int i = blockIdx.x * 256 + t;
    int d = (i < n) ? deg[i] : 0;
    arr[t] = d;
    __syncthreads();
#pragma unroll
    for (int off = 1; off < 256; off <<= 1) {
        int v = arr[t];
        int add = (t >= off) ? arr[t - off] : 0;
        __syncthreads();
        arr[t] = v + add;
        __syncthreads();
    }
    if (i < n) {
        int pos = boff[blockIdx.x] + arr[t] - d;   // exclusive prefix
        row_ptr[i] = pos;
        cursor[i] = pos;
        dinv[i] = rsqrtf((float)d);
    }
}

// 4) fill CSR columns (edges + implicit self-loops)
__global__ void fill_kernel(const int* __restrict__ src, const int* __restrict__ dst,
                            int* __restrict__ cursor, int* __restrict__ col,
                            int E, int EN) {
    int e = blockIdx.x * 256 + threadIdx.x;
    if (e >= EN) return;
    int s, d;
    if (e < E) { s = src[e]; d = dst[e]; }
    else       { s = e - E; d = s; }
    int pos = atomicAdd(&cursor[d], 1);
    col[pos] = s;
}

// 5) GEMM: out[r][:] = dinv[r] * (A[r][:] @ W), K chunked in halves of 64.
__global__ __launch_bounds__(256) void gemm_scale_kernel(const float* __restrict__ A,
                                                         const float* __restrict__ W,
                                                         const float* __restrict__ dinv,
                                                         float* __restrict__ out, int M) {
    __shared__ float sW[64][128];
    __shared__ float sA[64][68];
    int tid = threadIdx.x;
    int row0 = blockIdx.x * 64;
    int j0 = (tid & 31) * 4;
    int i0 = (tid >> 5) * 8;

    float acc[8][4];
#pragma unroll
    for (int ii = 0; ii < 8; ++ii)
#pragma unroll
        for (int jj = 0; jj < 4; ++jj) acc[ii][jj] = 0.f;

    for (int kc = 0; kc < 2; ++kc) {
        for (int idx = tid * 4; idx < 64 * 128; idx += 1024)
            *(float4*)(&sW[0][0] + idx) = *(const float4*)(W + (size_t)kc * 64 * 128 + idx);
        for (int idx = tid * 4; idx < 64 * 64; idx += 1024) {
            int r = idx >> 6, c = idx & 63;
            float4 v = make_float4(0.f, 0.f, 0.f, 0.f);
            if (row0 + r < M) v = *(const float4*)(A + (size_t)(row0 + r) * 128 + kc * 64 + c);
            *(float4*)&sA[r][c] = v;
        }
        __syncthreads();

        for (int k = 0; k < 64; k += 4) {
            float4 w0 = *(float4*)&sW[k + 0][j0];
            float4 w1 = *(float4*)&sW[k + 1][j0];
            float4 w2 = *(float4*)&sW[k + 2][j0];
            float4 w3 = *(float4*)&sW[k + 3][j0];
#pragma unroll
            for (int ii = 0; ii < 8; ++ii) {
                float4 a = *(float4*)&sA[i0 + ii][k];
                acc[ii][0] += a.x * w0.x + a.y * w1.x + a.z * w2.x + a.w * w3.x;
                acc[ii][1] += a.x * w0.y + a.y * w1.y + a.z * w2.y + a.w * w3.y;
                acc[ii][2] += a.x * w0.z + a.y * w1.z + a.z * w2.z + a.w * w3.z;
                acc[ii][3] += a.x * w0.w + a.y * w1.w + a.z * w2.w + a.w * w3.w;
            }
        }
        __syncthreads();
    }

#pragma unroll
    for (int ii = 0; ii < 8; ++ii) {
        int r = row0 + i0 + ii;
        if (r < M) {
            float dv = dinv[r];
            float4 o;
            o.x = acc[ii][0] * dv; o.y = acc[ii][1] * dv;
            o.z = acc[ii][2] * dv; o.w = acc[ii][3] * dv;
            *(float4*)(out + (size_t)r * 128 + j0) = o;
        }
    }
}

// 6) aggregation: out[v][:] = relu(dinv[v] * sum_{s in N(v)} hw[s][:] + b)
//    4-deep edge unroll: 4 independent float4 gathers in flight per 32-lane group.
__global__ __launch_bounds__(256) void aggregate_kernel(const float* __restrict__ hw,
                                                        const int* __restrict__ row_ptr,
                                                        const int* __restrict__ col,
                                                        const float* __restrict__ dinv,
                                                        const float* __restrict__ bias,
                                                        float* __restrict__ out, int n) {
    int tid = threadIdx.x;
    int v = blockIdx.x * 8 + (tid >> 5);
    if (v >= n) return;
    int j = (tid & 31) * 4;
    int p0 = row_ptr[v], p1 = row_ptr[v + 1];
    float4 acc = make_float4(0.f, 0.f, 0.f, 0.f);
    int p = p0;
    for (; p + 3 < p1; p += 4) {
        int s0 = col[p], s1 = col[p + 1], s2 = col[p + 2], s3 = col[p + 3];
        float4 a = *(const float4*)(hw + (size_t)s0 * 128 + j);
        float4 b = *(const float4*)(hw + (size_t)s1 * 128 + j);
        float4 c = *(const float4*)(hw + (size_t)s2 * 128 + j);
        float4 d = *(const float4*)(hw + (size_t)s3 * 128 + j);
        acc.x += (a.x + b.x) + (c.x + d.x);
        acc.y += (a.y + b.y) + (c.y + d.y);
        acc.z += (a.z + b.z) + (c.z + d.z);
        acc.w += (a.w + b.w) + (c.w + d.w);
    }
    for (; p < p1; ++p) {
        int s0 = col[p];
        float4 a = *(const float4*)(hw + (size_t)s0 * 128 + j);
        acc.x += a.x; acc.y += a.y; acc.z += a.z; acc.w += a.w;
    }
    float dv = dinv[v];
    float4 bb = *(const float4*)(bias + j);
    float4 o;
    o.x = fmaxf(acc.x * dv + bb.x, 0.f);
    o.y = fmaxf(acc.y * dv + bb.y, 0.f);
    o.z = fmaxf(acc.z * dv + bb.z, 0.f);
    o.w = fmaxf(acc.w * dv + bb.w, 0.f);
    *(float4*)(out + (size_t)v * 128 + j) = o;
}

// 7) graph boundary detection (batch sorted)
__global__ void boundary_kernel(const int* __restrict__ batch, int* __restrict__ start, int n) {
    int i = blockIdx.x * 256 + threadIdx.x;
    if (i >= n) return;
    int b = batch[i];
    int pb = (i > 0) ? batch[i - 1] : -1;
    if (b != pb) {
        for (int g = pb + 1; g <= b; ++g) start[g] = i;
    }
    if (i == n - 1) {
        for (int g = b + 1; g <= N_GRAPHS; ++g) start[g] = n;
    }
}

// 8) pooled mean per graph: one block per graph, no atomics
__global__ __launch_bounds__(256) void pool_reduce_kernel(const float* __restrict__ h,
                                                          const int* __restrict__ start,
                                                          float* __restrict__ pooled) {
    __shared__ float part[8][128];
    int g = blockIdx.x;
    int s = start[g], e = start[g + 1];
    int tid = threadIdx.x;
    int grp = tid >> 5;
    int j = (tid & 31) * 4;
    float4 acc = make_float4(0.f, 0.f, 0.f, 0.f);
    for (int v = s + grp; v < e; v += 8) {
        float4 a = *(const float4*)(h + (size_t)v * 128 + j);
        acc.x += a.x; acc.y += a.y; acc.z += a.z; acc.w += a.w;
    }
    *(float4*)&part[grp][j] = acc;
    __syncthreads();
    if (tid < 128) {
        float sum = 0.f;
#pragma unroll
        for (int k = 0; k < 8; ++k) sum += part[k][tid];
        int cntv = e - s; if (cntv < 1) cntv = 1;
        pooled[g * 128 + tid] = sum / (float)cntv;
    }
}

// 9) final MLP
__global__ __launch_bounds__(256) void mlp_kernel(const float* __restrict__ pooled_g,
                                                  const float* __restrict__ W1,
                                                  const float* __restrict__ b1,
                                                  const float* __restrict__ W2,
                                                  const float* __restrict__ b2,
                                                  float* __restrict__ out) {
    __shared__ float pooled[64][128];
    __shared__ float h1[64][64];
    int tid = threadIdx.x;
    for (int i = tid; i < 64 * 128; i += 256) pooled[i >> 7][i & 127] = pooled_g[i];
    __syncthreads();
    for (int i = tid; i < 64 * 64; i += 256) {
        int g = i >> 6, j = i & 63;
        float acc = b1[j];
        for (int k = 0; k < 128; ++k) acc += pooled[g][k] * W1[k * 64 + j];
        h1[g][j] = fmaxf(acc, 0.f);
    }
    __syncthreads();
    if (tid < 128) {
        int g = tid >> 1, c = tid & 1;
        float acc = b2[c];
        for (int jj = 0; jj < 64; ++jj) acc += h1[g][jj] * W2[jj * 2 + c];
        out[tid] = acc;
    }
}

// ---------------------------------------------------------------------------
extern "C" void kernel_launch(void* const* d_in, const int* in_sizes, int n_in,
                              void* d_out, int out_size, void* d_ws, size_t ws_size,
                              hipStream_t stream) {
    const float* x    = (const float*)d_in[0];
    const int*   ei   = (const int*)d_in[1];
    const int*   batch= (const int*)d_in[2];
    const float* W0   = (const float*)d_in[3];
    const float* b0   = (const float*)d_in[4];
    const float* Ws   = (const float*)d_in[5];
    const float* bs   = (const float*)d_in[6];
    const float* W1   = (const float*)d_in[7];
    const float* b1   = (const float*)d_in[8];
    const float* W2   = (const float*)d_in[9];
    const float* b2   = (const float*)d_in[10];
    float* out = (float*)d_out;

    const int n  = in_sizes[0] / HID;      // 50000
    const int E  = in_sizes[1] / 2;        // 800000
    const int EN = E + n;                  // 850000
    const int* src = ei;
    const int* dst = ei + E;
    const int nb = (n + 255) / 256;        // 196 blocks

    char* ws = (char*)d_ws;
    size_t off = 0;
    auto alloc = [&](size_t bytes) { void* p = ws + off; off = (off + bytes + 255) & ~(size_t)255; return p; };
    float* bufA   = (float*)alloc((size_t)n * HID * 4);
    float* bufB   = (float*)alloc((size_t)n * HID * 4);
    float* dinv   = (float*)alloc((size_t)n * 4);
    int*   row_ptr= (int*)  alloc((size_t)(n + 1) * 4);
    int*   cursor = (int*)  alloc((size_t)n * 4);
    int*   deg    = (int*)  alloc((size_t)n * 4);
    int*   col    = (int*)  alloc((size_t)EN * 4);
    int*   bsum   = (int*)  alloc((size_t)nb * 4);
    int*   boff   = (int*)  alloc((size_t)nb * 4);
    int*   gstart = (int*)  alloc((N_GRAPHS + 1) * 4);
    float* pooled = (float*)alloc(N_GRAPHS * 128 * 4);
    (void)ws_size; (void)n_in; (void)out_size;

    // --- build normalized CSR ---
    init_deg_kernel<<<nb, 256, 0, stream>>>(deg, n);
    count_kernel<<<(E + 255) / 256, 256, 0, stream>>>(dst, deg, E);
    scan_partial_kernel<<<nb, 256, 0, stream>>>(deg, bsum, n);
    scan_bsum_kernel<<<1, 256, 0, stream>>>(bsum, boff, row_ptr, nb, n);
    scan_emit_kernel<<<nb, 256, 0, stream>>>(deg, boff, row_ptr, cursor, dinv, n);
    fill_kernel<<<(EN + 255) / 256, 256, 0, stream>>>(src, dst, cursor, col, E, EN);
    boundary_kernel<<<nb, 256, 0, stream>>>(batch, gstart, n);

    const int gemm_grid = (n + 63) / 64;
    const int node_grid = (n + 7) / 8;

    // --- layer 0 ---
    gemm_scale_kernel<<<gemm_grid, 256, 0, stream>>>(x, W0, dinv, bufB, n);
    aggregate_kernel<<<node_grid, 256, 0, stream>>>(bufB, row_ptr, col, dinv, b0, bufA, n);
    // --- layers 1..3 ---
    for (int l = 0; l < 3; ++l) {
        gemm_scale_kernel<<<gemm_grid, 256, 0, stream>>>(bufA, Ws + (size_t)l * HID * HID, dinv, bufB, n);
        aggregate_kernel<<<node_grid, 256, 0, stream>>>(bufB, row_ptr, col, dinv, bs + (size_t)l * HID, bufA, n);
    }

    // --- pooling + MLP ---
    pool_reduce_kernel<<<N_GRAPHS, 256, 0, stream>>>(bufA, gstart, pooled);
    mlp_kernel<<<1, 256, 0, stream>>>(pooled, W1, b1, W2, b2, out);
}

// Round 6
// 606.918 us; speedup vs baseline: 1.9329x; 1.0075x over previous
//
#include <hip/hip_runtime.h>
#include <hip/hip_bf16.h>

#define HID 128
#define N_GRAPHS 64

// ---------------------------------------------------------------------------
// 1) degree init (self-loop counts as 1)
__global__ void init_deg_kernel(int* __restrict__ deg, int n) {
    int i = blockIdx.x * 256 + threadIdx.x;
    if (i < n) deg[i] = 1;
}

// 2) count in-degrees from dst row of edge_index
__global__ void count_kernel(const int* __restrict__ dst, int* __restrict__ deg, int E) {
    int e = blockIdx.x * 256 + threadIdx.x;
    if (e < E) atomicAdd(&deg[dst[e]], 1);
}

// 3a) per-block partial sums of deg
__global__ __launch_bounds__(256) void scan_partial_kernel(const int* __restrict__ deg,
                                                           int* __restrict__ bsum, int n) {
    __shared__ int red[256];
    int t = threadIdx.x;
    int i = blockIdx.x * 256 + t;
    red[t] = (i < n) ? deg[i] : 0;
    __syncthreads();
#pragma unroll
    for (int s = 128; s > 0; s >>= 1) {
        if (t < s) red[t] += red[t + s];
        __syncthreads();
    }
    if (t == 0) bsum[blockIdx.x] = red[0];
}

// 3b) single-block exclusive scan of block sums (nb <= 256); also writes row_ptr[n]
__global__ __launch_bounds__(256) void scan_bsum_kernel(const int* __restrict__ bsum,
                                                        int* __restrict__ boff,
                                                        int* __restrict__ row_ptr,
                                                        int nb, int n) {
    __shared__ int arr[256];
    int t = threadIdx.x;
    int own = (t < nb) ? bsum[t] : 0;
    arr[t] = own;
    __syncthreads();
#pragma unroll
    for (int off = 1; off < 256; off <<= 1) {
        int v = arr[t];
        int add = (t >= off) ? arr[t - off] : 0;
        __syncthreads();
        arr[t] = v + add;
        __syncthreads();
    }
    if (t < nb) boff[t] = arr[t] - own;        // exclusive
    if (t == 255) row_ptr[n] = arr[255];       // total
}

// 3c) emit row_ptr/cursor/dinv via in-block exclusive scan + block offset
__global__ __launch_bounds__(256) void scan_emit_kernel(const int* __restrict__ deg,
                                                        const int* __restrict__ boff,
                                                        int* __restrict__ row_ptr,
                                                        int* __restrict__ cursor,
                                                        float* __restrict__ dinv, int n) {
    __shared__ int arr[256];
    int t = threadIdx.x;
    int i = blockIdx.x * 256 + t;
    int d = (i < n) ? deg[i] : 0;
    arr[t] = d;
    __syncthreads();
#pragma unroll
    for (int off = 1; off < 256; off <<= 1) {
        int v = arr[t];
        int add = (t >= off) ? arr[t - off] : 0;
        __syncthreads();
        arr[t] = v + add;
        __syncthreads();
    }
    if (i < n) {
        int pos = boff[blockIdx.x] + arr[t] - d;   // exclusive prefix
        row_ptr[i] = pos;
        cursor[i] = pos;
        dinv[i] = rsqrtf((float)d);
    }
}

// 4) fill CSR columns (edges + implicit self-loops)
__global__ void fill_kernel(const int* __restrict__ src, const int* __restrict__ dst,
                            int* __restrict__ cursor, int* __restrict__ col,
                            int E, int EN) {
    int e = blockIdx.x * 256 + threadIdx.x;
    if (e >= EN) return;
    int s, d;
    if (e < E) { s = src[e]; d = dst[e]; }
    else       { s = e - E; d = s; }
    int pos = atomicAdd(&cursor[d], 1);
    col[pos] = s;
}

// 5) GEMM: out[r][:] = dinv[r] * (A[r][:] @ W)
//    128x128 tile, 8x8 per thread, BK=32, A staged transposed in LDS.
//    Thread (ty,tx): rows r0=ty*8..+7, cols {tx*4..+3, 64+tx*4..+3}.
__global__ __launch_bounds__(256, 4) void gemm_scale_kernel(const float* __restrict__ A,
                                                            const float* __restrict__ W,
                                                            const float* __restrict__ dinv,
                                                            float* __restrict__ out, int M) {
    __shared__ float sAT[32][132];   // [k][row], 16.9 KB
    __shared__ float sW[32][132];    // [k][col], 16.9 KB
    int tid = threadIdx.x;
    int row0 = blockIdx.x * 128;
    int ty = tid >> 4, tx = tid & 15;
    int r0 = ty * 8;
    int cl = tx * 4;          // low col group
    int ch = 64 + tx * 4;     // high col group

    float acc[8][8];
#pragma unroll
    for (int i = 0; i < 8; ++i)
#pragma unroll
        for (int j = 0; j < 8; ++j) acc[i][j] = 0.f;

    for (int kc = 0; kc < 128; kc += 32) {
        // stage W chunk [32][128] (coalesced, direct)
#pragma unroll
        for (int p = 0; p < 4; ++p) {
            int idx = tid + p * 256;              // 0..1023
            int k = idx >> 5, c4 = idx & 31;
            float4 v = *(const float4*)(W + (size_t)(kc + k) * 128 + c4 * 4);
            *(float4*)&sW[k][c4 * 4] = v;
        }
        // stage A chunk transposed: sAT[k][row]
#pragma unroll
        for (int p = 0; p < 4; ++p) {
            int idx = tid + p * 256;              // 0..1023
            int r = idx >> 3, c4 = idx & 7;
            float4 v = make_float4(0.f, 0.f, 0.f, 0.f);
            if (row0 + r < M) v = *(const float4*)(A + (size_t)(row0 + r) * 128 + kc + c4 * 4);
            sAT[c4 * 4 + 0][r] = v.x;
            sAT[c4 * 4 + 1][r] = v.y;
            sAT[c4 * 4 + 2][r] = v.z;
            sAT[c4 * 4 + 3][r] = v.w;
        }
        __syncthreads();

#pragma unroll 4
        for (int k = 0; k < 32; ++k) {
            float4 a0 = *(float4*)&sAT[k][r0];
            float4 a1 = *(float4*)&sAT[k][r0 + 4];
            float4 w0 = *(float4*)&sW[k][cl];
            float4 w1 = *(float4*)&sW[k][ch];
            float a[8] = {a0.x, a0.y, a0.z, a0.w, a1.x, a1.y, a1.z, a1.w};
            float w[8] = {w0.x, w0.y, w0.z, w0.w, w1.x, w1.y, w1.z, w1.w};
#pragma unroll
            for (int i = 0; i < 8; ++i)
#pragma unroll
                for (int j = 0; j < 8; ++j)
                    acc[i][j] += a[i] * w[j];
        }
        __syncthreads();
    }

#pragma unroll
    for (int i = 0; i < 8; ++i) {
        int r = row0 + r0 + i;
        if (r < M) {
            float dv = dinv[r];
            float4 lo, hi;
            lo.x = acc[i][0] * dv; lo.y = acc[i][1] * dv;
            lo.z = acc[i][2] * dv; lo.w = acc[i][3] * dv;
            hi.x = acc[i][4] * dv; hi.y = acc[i][5] * dv;
            hi.z = acc[i][6] * dv; hi.w = acc[i][7] * dv;
            *(float4*)(out + (size_t)r * 128 + cl) = lo;
            *(float4*)(out + (size_t)r * 128 + ch) = hi;
        }
    }
}

// 6) aggregation: out[v][:] = relu(dinv[v] * sum_{s in N(v)} hw[s][:] + b)
__global__ __launch_bounds__(256) void aggregate_kernel(const float* __restrict__ hw,
                                                        const int* __restrict__ row_ptr,
                                                        const int* __restrict__ col,
                                                        const float* __restrict__ dinv,
                                                        const float* __restrict__ bias,
                                                        float* __restrict__ out, int n) {
    int tid = threadIdx.x;
    int v = blockIdx.x * 8 + (tid >> 5);
    if (v >= n) return;
    int j = (tid & 31) * 4;
    int p0 = row_ptr[v], p1 = row_ptr[v + 1];
    float4 acc = make_float4(0.f, 0.f, 0.f, 0.f);
    int p = p0;
    for (; p + 3 < p1; p += 4) {
        int s0 = col[p], s1 = col[p + 1], s2 = col[p + 2], s3 = col[p + 3];
        float4 a = *(const float4*)(hw + (size_t)s0 * 128 + j);
        float4 b = *(const float4*)(hw + (size_t)s1 * 128 + j);
        float4 c = *(const float4*)(hw + (size_t)s2 * 128 + j);
        float4 d = *(const float4*)(hw + (size_t)s3 * 128 + j);
        acc.x += (a.x + b.x) + (c.x + d.x);
        acc.y += (a.y + b.y) + (c.y + d.y);
        acc.z += (a.z + b.z) + (c.z + d.z);
        acc.w += (a.w + b.w) + (c.w + d.w);
    }
    for (; p < p1; ++p) {
        int s0 = col[p];
        float4 a = *(const float4*)(hw + (size_t)s0 * 128 + j);
        acc.x += a.x; acc.y += a.y; acc.z += a.z; acc.w += a.w;
    }
    float dv = dinv[v];
    float4 bb = *(const float4*)(bias + j);
    float4 o;
    o.x = fmaxf(acc.x * dv + bb.x, 0.f);
    o.y = fmaxf(acc.y * dv + bb.y, 0.f);
    o.z = fmaxf(acc.z * dv + bb.z, 0.f);
    o.w = fmaxf(acc.w * dv + bb.w, 0.f);
    *(float4*)(out + (size_t)v * 128 + j) = o;
}

// 7) graph boundary detection (batch sorted)
__global__ void boundary_kernel(const int* __restrict__ batch, int* __restrict__ start, int n) {
    int i = blockIdx.x * 256 + threadIdx.x;
    if (i >= n) return;
    int b = batch[i];
    int pb = (i > 0) ? batch[i - 1] : -1;
    if (b != pb) {
        for (int g = pb + 1; g <= b; ++g) start[g] = i;
    }
    if (i == n - 1) {
        for (int g = b + 1; g <= N_GRAPHS; ++g) start[g] = n;
    }
}

// 8) pooled mean per graph: one block per graph, no atomics
__global__ __launch_bounds__(256) void pool_reduce_kernel(const float* __restrict__ h,
                                                          const int* __restrict__ start,
                                                          float* __restrict__ pooled) {
    __shared__ float part[8][128];
    int g = blockIdx.x;
    int s = start[g], e = start[g + 1];
    int tid = threadIdx.x;
    int grp = tid >> 5;
    int j = (tid & 31) * 4;
    float4 acc = make_float4(0.f, 0.f, 0.f, 0.f);
    for (int v = s + grp; v < e; v += 8) {
        float4 a = *(const float4*)(h + (size_t)v * 128 + j);
        acc.x += a.x; acc.y += a.y; acc.z += a.z; acc.w += a.w;
    }
    *(float4*)&part[grp][j] = acc;
    __syncthreads();
    if (tid < 128) {
        float sum = 0.f;
#pragma unroll
        for (int k = 0; k < 8; ++k) sum += part[k][tid];
        int cntv = e - s; if (cntv < 1) cntv = 1;
        pooled[g * 128 + tid] = sum / (float)cntv;
    }
}

// 9) final MLP
__global__ __launch_bounds__(256) void mlp_kernel(const float* __restrict__ pooled_g,
                                                  const float* __restrict__ W1,
                                                  const float* __restrict__ b1,
                                                  const float* __restrict__ W2,
                                                  const float* __restrict__ b2,
                                                  float* __restrict__ out) {
    __shared__ float pooled[64][128];
    __shared__ float h1[64][64];
    int tid = threadIdx.x;
    for (int i = tid; i < 64 * 128; i += 256) pooled[i >> 7][i & 127] = pooled_g[i];
    __syncthreads();
    for (int i = tid; i < 64 * 64; i += 256) {
        int g = i >> 6, j = i & 63;
        float acc = b1[j];
        for (int k = 0; k < 128; ++k) acc += pooled[g][k] * W1[k * 64 + j];
        h1[g][j] = fmaxf(acc, 0.f);
    }
    __syncthreads();
    if (tid < 128) {
        int g = tid >> 1, c = tid & 1;
        float acc = b2[c];
        for (int jj = 0; jj < 64; ++jj) acc += h1[g][jj] * W2[jj * 2 + c];
        out[tid] = acc;
    }
}

// ---------------------------------------------------------------------------
extern "C" void kernel_launch(void* const* d_in, const int* in_sizes, int n_in,
                              void* d_out, int out_size, void* d_ws, size_t ws_size,
                              hipStream_t stream) {
    const float* x    = (const float*)d_in[0];
    const int*   ei   = (const int*)d_in[1];
    const int*   batch= (const int*)d_in[2];
    const float* W0   = (const float*)d_in[3];
    const float* b0   = (const float*)d_in[4];
    const float* Ws   = (const float*)d_in[5];
    const float* bs   = (const float*)d_in[6];
    const float* W1   = (const float*)d_in[7];
    const float* b1   = (const float*)d_in[8];
    const float* W2   = (const float*)d_in[9];
    const float* b2   = (const float*)d_in[10];
    float* out = (float*)d_out;

    const int n  = in_sizes[0] / HID;      // 50000
    const int E  = in_sizes[1] / 2;        // 800000
    const int EN = E + n;                  // 850000
    const int* src = ei;
    const int* dst = ei + E;
    const int nb = (n + 255) / 256;        // 196 blocks

    char* ws = (char*)d_ws;
    size_t off = 0;
    auto alloc = [&](size_t bytes) { void* p = ws + off; off = (off + bytes + 255) & ~(size_t)255; return p; };
    float* bufA   = (float*)alloc((size_t)n * HID * 4);
    float* bufB   = (float*)alloc((size_t)n * HID * 4);
    float* dinv   = (float*)alloc((size_t)n * 4);
    int*   row_ptr= (int*)  alloc((size_t)(n + 1) * 4);
    int*   cursor = (int*)  alloc((size_t)n * 4);
    int*   deg    = (int*)  alloc((size_t)n * 4);
    int*   col    = (int*)  alloc((size_t)EN * 4);
    int*   bsum   = (int*)  alloc((size_t)nb * 4);
    int*   boff   = (int*)  alloc((size_t)nb * 4);
    int*   gstart = (int*)  alloc((N_GRAPHS + 1) * 4);
    float* pooled = (float*)alloc(N_GRAPHS * 128 * 4);
    (void)ws_size; (void)n_in; (void)out_size;

    // --- build normalized CSR ---
    init_deg_kernel<<<nb, 256, 0, stream>>>(deg, n);
    count_kernel<<<(E + 255) / 256, 256, 0, stream>>>(dst, deg, E);
    scan_partial_kernel<<<nb, 256, 0, stream>>>(deg, bsum, n);
    scan_bsum_kernel<<<1, 256, 0, stream>>>(bsum, boff, row_ptr, nb, n);
    scan_emit_kernel<<<nb, 256, 0, stream>>>(deg, boff, row_ptr, cursor, dinv, n);
    fill_kernel<<<(EN + 255) / 256, 256, 0, stream>>>(src, dst, cursor, col, E, EN);
    boundary_kernel<<<nb, 256, 0, stream>>>(batch, gstart, n);

    const int gemm_grid = (n + 127) / 128;
    const int node_grid = (n + 7) / 8;

    // --- layer 0 ---
    gemm_scale_kernel<<<gemm_grid, 256, 0, stream>>>(x, W0, dinv, bufB, n);
    aggregate_kernel<<<node_grid, 256, 0, stream>>>(bufB, row_ptr, col, dinv, b0, bufA, n);
    // --- layers 1..3 ---
    for (int l = 0; l < 3; ++l) {
        gemm_scale_kernel<<<gemm_grid, 256, 0, stream>>>(bufA, Ws + (size_t)l * HID * HID, dinv, bufB, n);
        aggregate_kernel<<<node_grid, 256, 0, stream>>>(bufB, row_ptr, col, dinv, bs + (size_t)l * HID, bufA, n);
    }

    // --- pooling + MLP ---
    pool_reduce_kernel<<<N_GRAPHS, 256, 0, stream>>>(bufA, gstart, pooled);
    mlp_kernel<<<1, 256, 0, stream>>>(pooled, W1, b1, W2, b2, out);
}